// Round 7
// baseline (534.810 us; speedup 1.0000x reference)
//
#include <hip/hip_runtime.h>

#define G_GENES 2000
#define T_TF    64
#define P_PEAKS 21000
#define B_BATCH 64
#define H_DIM   3000   // NUM_GOS * GO_DIM
#define N_OUT   7

typedef float v4f __attribute__((ext_vector_type(4)));

#define KSPLIT 10
#define KCH    (G_GENES / KSPLIT)   // 200
#define KK_CH  25

// ---------------- workspace layout (floats) ----------------
#define WS_XCAT 0                               // B*G = 128000 (zeroed by transpose_w)
#define WS_WT   128000                          // T*P = 1344000
#define WS_AT   (128000 + 1344000)              // G*B = 128000 (x_cat transposed)
#define WS_HP   (128000 + 1344000 + 128000)     // KSPLIT * B*H = 1920000 partials

// ---------------- d_out layout (floats) ----------------
// [0, 128000) x_cat | [128000, 320000) h | [320000, 320448) out

// Tiled transpose W_peaks[P][T] -> Wt[T][P]; idle capacity zeroes xcat_acc.
__global__ __launch_bounds__(256) void transpose_w(const float* __restrict__ W,
                                                   float* __restrict__ Wt,
                                                   float* __restrict__ xcat_acc) {
    const int gid = blockIdx.x * 256 + threadIdx.x;
    if (gid < (B_BATCH * G_GENES) / 4)
        ((float4*)xcat_acc)[gid] = make_float4(0.f, 0.f, 0.f, 0.f);

    __shared__ float tile[64][65];
    const int pBase = blockIdx.x * 64;
    const int tid = threadIdx.x;
    const int lane = tid & 63;
    const int grp  = tid >> 6;
#pragma unroll
    for (int i = 0; i < 16; ++i) {
        int pr = grp + i * 4;
        int p  = pBase + pr;
        if (p < P_PEAKS) tile[pr][lane] = W[(size_t)p * T_TF + lane];
    }
    __syncthreads();
#pragma unroll
    for (int i = 0; i < 16; ++i) {
        int tr = grp + i * 4;
        int p  = pBase + lane;
        if (p < P_PEAKS) Wt[(size_t)tr * P_PEAKS + p] = tile[lane][tr];
    }
}

// Main einsum + ragged segment-sum.
// grid = (21, 32, 2), block = 256. Thread: 4 peaks x 2 batches x 32 TFs.
// T-split (blockIdx.z) doubles resident waves (21/CU) for latency hiding at
// unchanged x/Wt traffic. NT loads on x: read-once stream > LLC; keeps L2/LLC
// clean for Wt re-reads (R5 measured: removing NT = +17 us).
__global__ __launch_bounds__(256) void peak_dot(const float* __restrict__ x,
                                                const float* __restrict__ Wt,
                                                const int*   __restrict__ gene_ids,
                                                float* __restrict__ xcat_acc) {
    const int p4 = blockIdx.x * 256 + threadIdx.x;
    if (p4 >= P_PEAKS / 4) return;
    const int b0 = blockIdx.y * 2;
    const int t0 = blockIdx.z * (T_TF / 2);
    const int p = p4 * 4;
    const int s4 = P_PEAKS / 4;              // 5250 v4f per t-row

    const int4 g = *(const int4*)(gene_ids + p);   // hoisted: overlaps with loop loads

    const v4f* __restrict__ wp = (const v4f*)(Wt + p) + (size_t)t0 * s4;
    const v4f* __restrict__ xp = (const v4f*)(x + (size_t)b0 * T_TF * P_PEAKS + p)
                                 + (size_t)t0 * s4;

    v4f acc0 = (v4f)0.f, acc1 = (v4f)0.f;
#pragma unroll 16
    for (int t = 0; t < T_TF / 2; ++t) {
        v4f wv = wp[t * s4];
        v4f x0 = __builtin_nontemporal_load(xp + t * s4);
        v4f x1 = __builtin_nontemporal_load(xp + (T_TF + t) * s4);
        acc0 += x0 * wv;
        acc1 += x1 * wv;
    }

#pragma unroll
    for (int bb = 0; bb < 2; ++bb) {
        v4f a = bb == 0 ? acc0 : acc1;
        float* dst = xcat_acc + (size_t)(b0 + bb) * G_GENES;
        float s = a.x; int cg = g.x;
        if (g.y == cg) s += a.y; else { atomicAdd(dst + cg, s); cg = g.y; s = a.y; }
        if (g.z == cg) s += a.z; else { atomicAdd(dst + cg, s); cg = g.z; s = a.z; }
        if (g.w == cg) s += a.w; else { atomicAdd(dst + cg, s); cg = g.w; s = a.w; }
        atomicAdd(dst + cg, s);
    }
}

// bias+relu -> x_cat output AND transposed At[g][b] for coalesced gemm1 staging
__global__ __launch_bounds__(256) void bias_relu_xcat(const float* __restrict__ acc,
                                                      const float* __restrict__ b_genes,
                                                      float* __restrict__ out,
                                                      float* __restrict__ At) {
    int i = blockIdx.x * 256 + threadIdx.x;
    if (i >= B_BATCH * G_GENES) return;
    int b = i / G_GENES;
    int g = i - b * G_GENES;
    float v = acc[i] + b_genes[g];
    v = v > 0.f ? v : 0.f;
    out[i] = v;
    At[(size_t)g * B_BATCH + b] = v;
}

// Split-K tiled fp32 GEMM: h_part[ks] = x_cat[64x2000(chunk)] @ W1[chunk x3000]
// Plain stores to per-split partial buffers. grid = (47, KSPLIT), block = 256.
__global__ __launch_bounds__(256) void gemm1(const float* __restrict__ At,
                                             const float* __restrict__ W1,
                                             float* __restrict__ h_part) {
    __shared__ __align__(16) float As[KK_CH][64];
    const int tid = threadIdx.x;
    const int tx = tid & 15;
    const int ty = tid >> 4;
    const int col0 = blockIdx.x * 64 + tx * 4;
    const int row0 = ty * 4;
    const int k0 = blockIdx.y * KCH;
    const bool colOK = (col0 < H_DIM);   // H_DIM % 4 == 0

    float4 acc4[4];
#pragma unroll
    for (int r = 0; r < 4; ++r) acc4[r] = make_float4(0.f, 0.f, 0.f, 0.f);

    for (int kc = 0; kc < KCH; kc += KK_CH) {
        __syncthreads();
        for (int idx = tid; idx < KK_CH * 64; idx += 256) {
            int kk = idx >> 6;
            int r  = idx & 63;
            As[kk][r] = At[(size_t)(k0 + kc + kk) * B_BATCH + r];
        }
        __syncthreads();
        if (colOK) {
#pragma unroll
            for (int kk = 0; kk < KK_CH; ++kk) {
                float4 a4 = *(const float4*)&As[kk][row0];
                float4 w4 = *(const float4*)&W1[(size_t)(k0 + kc + kk) * H_DIM + col0];
                acc4[0].x += a4.x * w4.x; acc4[0].y += a4.x * w4.y;
                acc4[0].z += a4.x * w4.z; acc4[0].w += a4.x * w4.w;
                acc4[1].x += a4.y * w4.x; acc4[1].y += a4.y * w4.y;
                acc4[1].z += a4.y * w4.z; acc4[1].w += a4.y * w4.w;
                acc4[2].x += a4.z * w4.x; acc4[2].y += a4.z * w4.y;
                acc4[2].z += a4.z * w4.z; acc4[2].w += a4.z * w4.w;
                acc4[3].x += a4.w * w4.x; acc4[3].y += a4.w * w4.y;
                acc4[3].z += a4.w * w4.z; acc4[3].w += a4.w * w4.w;
            }
        }
    }
    if (colOK) {
        float* dst = h_part + (size_t)blockIdx.y * (B_BATCH * H_DIM);
#pragma unroll
        for (int r = 0; r < 4; ++r)
            *(float4*)(dst + (size_t)(row0 + r) * H_DIM + col0) = acc4[r];
    }
}

// Fused tail: reduce KSPLIT partials + bias + relu -> h output (LDS-staged),
// then h @ W2 + b2 -> final out. One block per batch row.
__global__ __launch_bounds__(256) void tail(const float* __restrict__ h_part,
                                            const float* __restrict__ b1,
                                            const float* __restrict__ W2,
                                            const float* __restrict__ b2,
                                            float* __restrict__ out_h,
                                            float* __restrict__ out_fin) {
    const int b = blockIdx.x;
    const int tid = threadIdx.x;
    __shared__ float hrow[H_DIM];                 // 12 KB

    for (int idx = tid; idx < H_DIM; idx += 256) {
        float v = b1[idx];
#pragma unroll
        for (int s = 0; s < KSPLIT; ++s)
            v += h_part[(size_t)s * (B_BATCH * H_DIM) + (size_t)b * H_DIM + idx];
        v = v > 0.f ? v : 0.f;
        out_h[(size_t)b * H_DIM + idx] = v;
        hrow[idx] = v;
    }
    __syncthreads();

    float acc[N_OUT];
#pragma unroll
    for (int o = 0; o < N_OUT; ++o) acc[o] = 0.f;
    for (int k = tid; k < H_DIM; k += 256) {
        float hv = hrow[k];
#pragma unroll
        for (int o = 0; o < N_OUT; ++o) acc[o] += hv * W2[k * N_OUT + o];
    }
#pragma unroll
    for (int o = 0; o < N_OUT; ++o)
#pragma unroll
        for (int s = 32; s > 0; s >>= 1) acc[o] += __shfl_down(acc[o], s, 64);
    __shared__ float red[4][N_OUT];
    const int wave = tid >> 6;
    const int lane = tid & 63;
    if (lane == 0)
#pragma unroll
        for (int o = 0; o < N_OUT; ++o) red[wave][o] = acc[o];
    __syncthreads();
    if (tid < N_OUT)
        out_fin[(size_t)b * N_OUT + tid] =
            red[0][tid] + red[1][tid] + red[2][tid] + red[3][tid] + b2[tid];
}

extern "C" void kernel_launch(void* const* d_in, const int* in_sizes, int n_in,
                              void* d_out, int out_size, void* d_ws, size_t ws_size,
                              hipStream_t stream) {
    const float* x       = (const float*)d_in[0];
    const float* W_peaks = (const float*)d_in[1];
    const float* b_genes = (const float*)d_in[2];
    const float* W1      = (const float*)d_in[3];
    const float* b1      = (const float*)d_in[4];
    const float* W2      = (const float*)d_in[5];
    const float* b2      = (const float*)d_in[6];
    const int*   gene_ids = (const int*)d_in[7];

    float* ws = (float*)d_ws;
    float* xcat_acc = ws + WS_XCAT;
    float* Wt       = ws + WS_WT;
    float* At       = ws + WS_AT;
    float* h_part   = ws + WS_HP;

    float* out_xcat = (float*)d_out;                 // [64,2000]
    float* out_h    = (float*)d_out + 128000;        // [64,3000]
    float* out_fin  = (float*)d_out + 320000;        // [64,7]

    // 1. transpose W_peaks -> Wt[T][P]  (also zero-inits xcat_acc)
    transpose_w<<<(P_PEAKS + 63) / 64, 256, 0, stream>>>(W_peaks, Wt, xcat_acc);

    // 2. main einsum + ragged segment-sum (NT x-loads, T-split for 21 waves/CU)
    dim3 g1((P_PEAKS / 4 + 255) / 256, B_BATCH / 2, 2);
    peak_dot<<<g1, 256, 0, stream>>>(x, Wt, gene_ids, xcat_acc);

    // 3. bias + relu -> x_cat output + transposed At
    bias_relu_xcat<<<(B_BATCH * G_GENES + 255) / 256, 256, 0, stream>>>(
        xcat_acc, b_genes, out_xcat, At);

    // 4. x_cat @ W1 (split-K=10, partial buffers, no atomics)
    dim3 g2((H_DIM + 63) / 64, KSPLIT);
    gemm1<<<g2, 256, 0, stream>>>(At, W1, h_part);

    // 5. fused: reduce partials + bias + relu -> h; h @ W2 + b2 -> out
    tail<<<B_BATCH, 256, 0, stream>>>(h_part, b1, W2, b2, out_h, out_fin);
}

// Round 8
// 524.694 us; speedup vs baseline: 1.0193x; 1.0193x over previous
//
#include <hip/hip_runtime.h>

#define G_GENES 2000
#define T_TF    64
#define P_PEAKS 21000
#define B_BATCH 64
#define H_DIM   3000   // NUM_GOS * GO_DIM
#define N_OUT   7

typedef float v4f __attribute__((ext_vector_type(4)));

#define KSPLIT 10
#define KCH    (G_GENES / KSPLIT)   // 200
#define KK_CH  25

// ---------------- workspace layout (floats) ----------------
#define WS_XCAT 0                               // B*G = 128000 (zeroed by transpose_w)
#define WS_WT   128000                          // T*P = 1344000
#define WS_AT   (128000 + 1344000)              // G*B = 128000 (x_cat transposed)
#define WS_HP   (128000 + 1344000 + 128000)     // KSPLIT * B*H = 1920000 partials

// ---------------- d_out layout (floats) ----------------
// [0, 128000) x_cat | [128000, 320000) h | [320000, 320448) out

// Tiled transpose W_peaks[P][T] -> Wt[T][P]; idle capacity zeroes xcat_acc.
__global__ __launch_bounds__(256) void transpose_w(const float* __restrict__ W,
                                                   float* __restrict__ Wt,
                                                   float* __restrict__ xcat_acc) {
    const int gid = blockIdx.x * 256 + threadIdx.x;
    if (gid < (B_BATCH * G_GENES) / 4)
        ((float4*)xcat_acc)[gid] = make_float4(0.f, 0.f, 0.f, 0.f);

    __shared__ float tile[64][65];
    const int pBase = blockIdx.x * 64;
    const int tid = threadIdx.x;
    const int lane = tid & 63;
    const int grp  = tid >> 6;
#pragma unroll
    for (int i = 0; i < 16; ++i) {
        int pr = grp + i * 4;
        int p  = pBase + pr;
        if (p < P_PEAKS) tile[pr][lane] = W[(size_t)p * T_TF + lane];
    }
    __syncthreads();
#pragma unroll
    for (int i = 0; i < 16; ++i) {
        int tr = grp + i * 4;
        int p  = pBase + lane;
        if (p < P_PEAKS) Wt[(size_t)tr * P_PEAKS + p] = tile[lane][tr];
    }
}

// Main einsum + ragged segment-sum.
// grid = (21, 32), block = 256. Thread: 4 peaks x 2 batches = 10.5 waves/CU
// (measured sweet spot: 5.25 was -6us worse in R2/R3 family, 21 was -5.7us
// worse in R7 — occupancy ladder saturated; kernel is HBM-stream-bound).
// NT loads on x: read-once 344 MB stream > LLC; keeps L2/LLC clean for the
// Wt re-reads (R5/R6 measured: NT is worth ~15-17 us).
__global__ __launch_bounds__(256) void peak_dot(const float* __restrict__ x,
                                                const float* __restrict__ Wt,
                                                const int*   __restrict__ gene_ids,
                                                float* __restrict__ xcat_acc) {
    const int p4 = blockIdx.x * 256 + threadIdx.x;
    if (p4 >= P_PEAKS / 4) return;
    const int b0 = blockIdx.y * 2;
    const int p = p4 * 4;
    const int s4 = P_PEAKS / 4;              // 5250 v4f per t-row

    const int4 g = *(const int4*)(gene_ids + p);   // hoisted: overlaps loop loads

    const v4f* __restrict__ wp = (const v4f*)(Wt + p);
    const v4f* __restrict__ xp = (const v4f*)(x + (size_t)b0 * T_TF * P_PEAKS + p);

    v4f acc0 = (v4f)0.f, acc1 = (v4f)0.f;
#pragma unroll 16
    for (int t = 0; t < T_TF; ++t) {
        v4f wv = wp[t * s4];
        v4f x0 = __builtin_nontemporal_load(xp + t * s4);
        v4f x1 = __builtin_nontemporal_load(xp + (T_TF + t) * s4);
        acc0 += x0 * wv;
        acc1 += x1 * wv;
    }

#pragma unroll
    for (int bb = 0; bb < 2; ++bb) {
        v4f a = bb == 0 ? acc0 : acc1;
        float* dst = xcat_acc + (size_t)(b0 + bb) * G_GENES;
        float s = a.x; int cg = g.x;
        if (g.y == cg) s += a.y; else { atomicAdd(dst + cg, s); cg = g.y; s = a.y; }
        if (g.z == cg) s += a.z; else { atomicAdd(dst + cg, s); cg = g.z; s = a.z; }
        if (g.w == cg) s += a.w; else { atomicAdd(dst + cg, s); cg = g.w; s = a.w; }
        atomicAdd(dst + cg, s);
    }
}

// bias+relu -> x_cat output AND transposed At[g][b] for coalesced gemm1 staging
__global__ __launch_bounds__(256) void bias_relu_xcat(const float* __restrict__ acc,
                                                      const float* __restrict__ b_genes,
                                                      float* __restrict__ out,
                                                      float* __restrict__ At) {
    int i = blockIdx.x * 256 + threadIdx.x;
    if (i >= B_BATCH * G_GENES) return;
    int b = i / G_GENES;
    int g = i - b * G_GENES;
    float v = acc[i] + b_genes[g];
    v = v > 0.f ? v : 0.f;
    out[i] = v;
    At[(size_t)g * B_BATCH + b] = v;
}

// Split-K tiled fp32 GEMM: h_part[ks] = x_cat[64x2000(chunk)] @ W1[chunk x3000]
// Plain stores to per-split partial buffers (R4: removing atomics = -17 us).
// grid = (47, KSPLIT), block = 256, 4x4 register tile per thread.
__global__ __launch_bounds__(256) void gemm1(const float* __restrict__ At,
                                             const float* __restrict__ W1,
                                             float* __restrict__ h_part) {
    __shared__ __align__(16) float As[KK_CH][64];
    const int tid = threadIdx.x;
    const int tx = tid & 15;
    const int ty = tid >> 4;
    const int col0 = blockIdx.x * 64 + tx * 4;
    const int row0 = ty * 4;
    const int k0 = blockIdx.y * KCH;
    const bool colOK = (col0 < H_DIM);   // H_DIM % 4 == 0

    float4 acc4[4];
#pragma unroll
    for (int r = 0; r < 4; ++r) acc4[r] = make_float4(0.f, 0.f, 0.f, 0.f);

    for (int kc = 0; kc < KCH; kc += KK_CH) {
        __syncthreads();
        for (int idx = tid; idx < KK_CH * 64; idx += 256) {
            int kk = idx >> 6;
            int r  = idx & 63;
            As[kk][r] = At[(size_t)(k0 + kc + kk) * B_BATCH + r];
        }
        __syncthreads();
        if (colOK) {
#pragma unroll
            for (int kk = 0; kk < KK_CH; ++kk) {
                float4 a4 = *(const float4*)&As[kk][row0];
                float4 w4 = *(const float4*)&W1[(size_t)(k0 + kc + kk) * H_DIM + col0];
                acc4[0].x += a4.x * w4.x; acc4[0].y += a4.x * w4.y;
                acc4[0].z += a4.x * w4.z; acc4[0].w += a4.x * w4.w;
                acc4[1].x += a4.y * w4.x; acc4[1].y += a4.y * w4.y;
                acc4[1].z += a4.y * w4.z; acc4[1].w += a4.y * w4.w;
                acc4[2].x += a4.z * w4.x; acc4[2].y += a4.z * w4.y;
                acc4[2].z += a4.z * w4.z; acc4[2].w += a4.z * w4.w;
                acc4[3].x += a4.w * w4.x; acc4[3].y += a4.w * w4.y;
                acc4[3].z += a4.w * w4.z; acc4[3].w += a4.w * w4.w;
            }
        }
    }
    if (colOK) {
        float* dst = h_part + (size_t)blockIdx.y * (B_BATCH * H_DIM);
#pragma unroll
        for (int r = 0; r < 4; ++r)
            *(float4*)(dst + (size_t)(row0 + r) * H_DIM + col0) = acc4[r];
    }
}

// Fused tail: reduce KSPLIT partials + bias + relu -> h output (LDS-staged),
// then h @ W2 + b2 -> final out. One block per batch row.
__global__ __launch_bounds__(256) void tail(const float* __restrict__ h_part,
                                            const float* __restrict__ b1,
                                            const float* __restrict__ W2,
                                            const float* __restrict__ b2,
                                            float* __restrict__ out_h,
                                            float* __restrict__ out_fin) {
    const int b = blockIdx.x;
    const int tid = threadIdx.x;
    __shared__ float hrow[H_DIM];                 // 12 KB

    for (int idx = tid; idx < H_DIM; idx += 256) {
        float v = b1[idx];
#pragma unroll
        for (int s = 0; s < KSPLIT; ++s)
            v += h_part[(size_t)s * (B_BATCH * H_DIM) + (size_t)b * H_DIM + idx];
        v = v > 0.f ? v : 0.f;
        out_h[(size_t)b * H_DIM + idx] = v;
        hrow[idx] = v;
    }
    __syncthreads();

    float acc[N_OUT];
#pragma unroll
    for (int o = 0; o < N_OUT; ++o) acc[o] = 0.f;
    for (int k = tid; k < H_DIM; k += 256) {
        float hv = hrow[k];
#pragma unroll
        for (int o = 0; o < N_OUT; ++o) acc[o] += hv * W2[k * N_OUT + o];
    }
#pragma unroll
    for (int o = 0; o < N_OUT; ++o)
#pragma unroll
        for (int s = 32; s > 0; s >>= 1) acc[o] += __shfl_down(acc[o], s, 64);
    __shared__ float red[4][N_OUT];
    const int wave = tid >> 6;
    const int lane = tid & 63;
    if (lane == 0)
#pragma unroll
        for (int o = 0; o < N_OUT; ++o) red[wave][o] = acc[o];
    __syncthreads();
    if (tid < N_OUT)
        out_fin[(size_t)b * N_OUT + tid] =
            red[0][tid] + red[1][tid] + red[2][tid] + red[3][tid] + b2[tid];
}

extern "C" void kernel_launch(void* const* d_in, const int* in_sizes, int n_in,
                              void* d_out, int out_size, void* d_ws, size_t ws_size,
                              hipStream_t stream) {
    const float* x       = (const float*)d_in[0];
    const float* W_peaks = (const float*)d_in[1];
    const float* b_genes = (const float*)d_in[2];
    const float* W1      = (const float*)d_in[3];
    const float* b1      = (const float*)d_in[4];
    const float* W2      = (const float*)d_in[5];
    const float* b2      = (const float*)d_in[6];
    const int*   gene_ids = (const int*)d_in[7];

    float* ws = (float*)d_ws;
    float* xcat_acc = ws + WS_XCAT;
    float* Wt       = ws + WS_WT;
    float* At       = ws + WS_AT;
    float* h_part   = ws + WS_HP;

    float* out_xcat = (float*)d_out;                 // [64,2000]
    float* out_h    = (float*)d_out + 128000;        // [64,3000]
    float* out_fin  = (float*)d_out + 320000;        // [64,7]

    // 1. transpose W_peaks -> Wt[T][P]  (also zero-inits xcat_acc)
    transpose_w<<<(P_PEAKS + 63) / 64, 256, 0, stream>>>(W_peaks, Wt, xcat_acc);

    // 2. main einsum + ragged segment-sum (NT x-loads, 10.5 waves/CU)
    dim3 g1((P_PEAKS / 4 + 255) / 256, B_BATCH / 2);
    peak_dot<<<g1, 256, 0, stream>>>(x, Wt, gene_ids, xcat_acc);

    // 3. bias + relu -> x_cat output + transposed At
    bias_relu_xcat<<<(B_BATCH * G_GENES + 255) / 256, 256, 0, stream>>>(
        xcat_acc, b_genes, out_xcat, At);

    // 4. x_cat @ W1 (split-K=10, partial buffers, no atomics)
    dim3 g2((H_DIM + 63) / 64, KSPLIT);
    gemm1<<<g2, 256, 0, stream>>>(At, W1, h_part);

    // 5. fused: reduce partials + bias + relu -> h; h @ W2 + b2 -> out
    tail<<<B_BATCH, 256, 0, stream>>>(h_part, b1, W2, b2, out_h, out_fin);
}